// Round 8
// baseline (211.359 us; speedup 1.0000x reference)
//
#include <hip/hip_runtime.h>
#include <hip/hip_bf16.h>
#include <math.h>

#define B_  16
#define N_  16
#define T_  48
#define C_  512
#define H_  8
#define HD_ 64
#define L_  768
#define BL_ 12288

typedef __attribute__((ext_vector_type(8))) short b16x8;
typedef __attribute__((ext_vector_type(4))) float f32x4;

__device__ __forceinline__ short f2b(float f) {
  __hip_bfloat16 h = __float2bfloat16(f);
  return *reinterpret_cast<short*>(&h);
}
// fast RNE float->bf16 (finite inputs)
__device__ __forceinline__ short brne(float f) {
  unsigned u = __float_as_uint(f);
  u += 0x7fffu + ((u >> 16) & 1u);
  return (short)(u >> 16);
}

// ---------------------------------------------------------------------------
// prep: blocks [0,3072) cast x fp32->bf16; blocks [3072,4096) cast+transpose
// weights into WT[mat][n][k] (Wq pre-scaled by 1/8).
// ---------------------------------------------------------------------------
__global__ __launch_bounds__(256) void prep_kernel(
    const float* __restrict__ x,
    const float* __restrict__ Wq, const float* __restrict__ Wk,
    const float* __restrict__ Wv, const float* __restrict__ Wo,
    short* __restrict__ xb, short* __restrict__ WT)
{
  __shared__ float tile[32][33];
  int blk = blockIdx.x;
  int tid = threadIdx.x;
  if (blk < 3072) {
    int i = blk * 256 + tid;
    const float4* src = (const float4*)(x + (size_t)i * 8);
    float4 a = src[0], b = src[1];
    short tmp[8] = {f2b(a.x), f2b(a.y), f2b(a.z), f2b(a.w),
                    f2b(b.x), f2b(b.y), f2b(b.z), f2b(b.w)};
    *(b16x8*)(xb + (size_t)i * 8) = *(b16x8*)tmp;
  } else {
    int idx = blk - 3072;
    int mat = idx >> 8, rem = idx & 255;
    const float* W = (mat == 0) ? Wq : (mat == 1) ? Wk : (mat == 2) ? Wv : Wo;
    float scale = (mat == 0) ? 0.125f : 1.0f;
    int k0 = (rem >> 4) * 32, n0 = (rem & 15) * 32;
    int tx = tid & 31, ty = tid >> 5;
    for (int i = ty; i < 32; i += 8) tile[i][tx] = W[(size_t)(k0 + i) * 512 + n0 + tx];
    __syncthreads();
    short* dst = WT + (size_t)mat * 262144;
    for (int i = ty; i < 32; i += 8)
      dst[(size_t)(n0 + i) * 512 + k0 + tx] = f2b(tile[tx][i] * scale);
  }
}

// ---------------------------------------------------------------------------
// QKV GEMM, time-major permuted M-rows (rr = pt*16+pn), LDS-staged epilogue,
// software-pipelined staging (next-tile loads issue under current MFMAs).
//   q2,k2: [b][h][t][n][d]   vT2: [b][h][d][t][n]
// ---------------------------------------------------------------------------
__global__ __launch_bounds__(256) void qkv_kernel(
    const short* __restrict__ xb, const short* __restrict__ WT,
    short* __restrict__ q2, short* __restrict__ k2, short* __restrict__ vT2)
{
  __shared__ short smem[8192];              // As/Bs in K-loop; Ls in epilogue
  short (*As)[32] = (short(*)[32])smem;
  short (*Bs)[32] = (short(*)[32])(smem + 4096);
  int tid = threadIdx.x;
  int w = tid >> 6, lane = tid & 63, n16 = lane & 15, quad = lane >> 4;
  int bm = blockIdx.x, bn = blockIdx.y;
  int mat = bn >> 2;
  int ncol0 = (bn & 3) * 128;
  const short* Wt = WT + (size_t)mat * 262144;
  int bq = bm / 6;
  int rr0 = (bm % 6) * 128;

  f32x4 zero4 = {0.f, 0.f, 0.f, 0.f};
  f32x4 acc[4][4];
  #pragma unroll
  for (int mt = 0; mt < 4; ++mt)
    #pragma unroll
    for (int nt = 0; nt < 4; ++nt) acc[mt][nt] = zero4;

  int srow = tid >> 1, sch = (tid & 1) * 16;
  int rr = rr0 + srow;
  int pt = rr >> 4, pn = rr & 15;           // permuted row -> l = pn*48+pt
  const short* ga = xb + ((size_t)bq * 768 + pn * 48 + pt) * 512 + sch;
  const short* gb = Wt + (size_t)(ncol0 + srow) * 512 + sch;
  int wm = (w >> 1) * 64, wn = (w & 1) * 64;

  b16x8 a0 = *(const b16x8*)(ga);
  b16x8 a1 = *(const b16x8*)(ga + 8);
  b16x8 b0 = *(const b16x8*)(gb);
  b16x8 b1 = *(const b16x8*)(gb + 8);

  for (int kt = 0; kt < 16; ++kt) {
    __syncthreads();
    *(b16x8*)&As[srow][sch]     = a0;
    *(b16x8*)&As[srow][sch + 8] = a1;
    *(b16x8*)&Bs[srow][sch]     = b0;
    *(b16x8*)&Bs[srow][sch + 8] = b1;
    __syncthreads();
    if (kt < 15) {                          // prefetch hides under MFMAs
      ga += 32; gb += 32;
      a0 = *(const b16x8*)(ga);
      a1 = *(const b16x8*)(ga + 8);
      b0 = *(const b16x8*)(gb);
      b1 = *(const b16x8*)(gb + 8);
    }
    b16x8 af[4], bf[4];
    #pragma unroll
    for (int mt = 0; mt < 4; ++mt) af[mt] = *(const b16x8*)&As[wm + mt * 16 + n16][quad * 8];
    #pragma unroll
    for (int nt = 0; nt < 4; ++nt) bf[nt] = *(const b16x8*)&Bs[wn + nt * 16 + n16][quad * 8];
    #pragma unroll
    for (int mt = 0; mt < 4; ++mt)
      #pragma unroll
      for (int nt = 0; nt < 4; ++nt)
        acc[mt][nt] = __builtin_amdgcn_mfma_f32_16x16x32_bf16(af[mt], bf[nt], acc[mt][nt], 0, 0, 0);
  }

  // epilogue: 4 chunks of 32 tile-rows staged through LDS, vector stores out
  short (*Ls)[136] = (short(*)[136])smem;
  for (int c = 0; c < 4; ++c) {
    __syncthreads();
    if ((w >> 1) == (c >> 1)) {
      int mtb = (c & 1) * 2;
      #pragma unroll
      for (int mi = 0; mi < 2; ++mi) {
        #pragma unroll
        for (int nt = 0; nt < 4; ++nt)
          #pragma unroll
          for (int r = 0; r < 4; ++r)
            Ls[mi * 16 + quad * 4 + r][wn + nt * 16 + n16] = f2b(acc[mtb + mi][nt][r]);
      }
    }
    __syncthreads();
    int rrc = rr0 + c * 32;
    if (mat != 2) {
      short* dst = (mat == 0) ? q2 : k2;
      int row = tid >> 3, c0 = (tid & 7) * 16;
      int hhg = (ncol0 + c0) >> 6, d0 = (ncol0 + c0) & 63;
      short* dp = dst + ((size_t)(bq * 8 + hhg) * 768 + rrc + row) * 64 + d0;
      *(b16x8*)dp       = *(b16x8*)&Ls[row][c0];
      *(b16x8*)(dp + 8) = *(b16x8*)&Ls[row][c0 + 8];
    } else {
      int cp = tid & 63, r8 = (tid >> 6) * 8;
      int c0 = 2 * cp;
      int hhg = (ncol0 + c0) >> 6, d0 = (ncol0 + c0) & 63;
      short t0[8], t1[8];
      #pragma unroll
      for (int j = 0; j < 8; ++j) { t0[j] = Ls[r8 + j][c0]; t1[j] = Ls[r8 + j][c0 + 1]; }
      short* dp = vT2 + ((size_t)(bq * 8 + hhg) * 64 + d0) * 768 + rrc + r8;
      *(b16x8*)dp         = *(b16x8*)t0;
      *(b16x8*)(dp + 768) = *(b16x8*)t1;
    }
  }
}

// ---------------------------------------------------------------------------
// Attention with SPLIT-K across the block's 2 waves. Block = (b,h,qt-pair);
// wave wv handles kt2 = wv, wv+2, ... (interleaved, balanced). No-max softmax
// => partials combine by pure addition (one barrier). Wave 0 finalizes band A
// (qt=pair), wave 1 band B (qt=47-pair).
// ---------------------------------------------------------------------------
__global__ __launch_bounds__(128) void attn_kernel(
    const short* __restrict__ q2, const short* __restrict__ k2,
    const short* __restrict__ vT2,
    const float* __restrict__ relT, const float* __restrict__ relP,
    short* __restrict__ yatt)
{
  __shared__ short P[2][2][16][40];     // [wave][band][qn][K+pad]
  __shared__ float btL[2][96];
  __shared__ float Ox[2][16][65];       // cross-wave partial O [band][qn][col]
  __shared__ float Ps[2][16];           // cross-wave partial psum [band][qn]

  int tid = threadIdx.x;
  int wv = tid >> 6, lane = tid & 63, n16 = lane & 15, quad = lane >> 4;
  int blk = blockIdx.x;
  int h = blk & 7;                      // XCD-locality
  int g = blk >> 3;                     // 0..383
  int pair = g % 24, b = g / 24;
  int qtA = pair, qtB = 47 - pair;
  int nA = (qtA + 2) >> 1, nB = (qtB + 2) >> 1;

  btL[wv][lane] = relT[(lane < 95 ? lane : 94) * 8 + h];
  if (lane < 32) btL[wv][64 + lane] = relT[((64 + lane) < 95 ? 64 + lane : 94) * 8 + h];

  float bp4[4];
  #pragma unroll
  for (int r = 0; r < 4; ++r)
    bp4[r] = relP[(n16 - quad * 4 - r + 15) * 8 + h];

  size_t bh = (size_t)(b * 8 + h);
  const short* qb = q2 + bh * 49152;
  const short* kb = k2 + bh * 49152;
  const short* vb = vT2 + bh * 49152;

  b16x8 qA0 = *(const b16x8*)(qb + (qtA * 16 + n16) * 64 + quad * 8);
  b16x8 qA1 = *(const b16x8*)(qb + (qtA * 16 + n16) * 64 + quad * 8 + 32);
  b16x8 qB0 = *(const b16x8*)(qb + (qtB * 16 + n16) * 64 + quad * 8);
  b16x8 qB1 = *(const b16x8*)(qb + (qtB * 16 + n16) * 64 + quad * 8 + 32);

  f32x4 zero4 = {0.f, 0.f, 0.f, 0.f};
  f32x4 oA[4], oB[4];
  float psA[4] = {0, 0, 0, 0}, psB[4] = {0, 0, 0, 0};
  #pragma unroll
  for (int nt = 0; nt < 4; ++nt) { oA[nt] = zero4; oB[nt] = zero4; }

  b16x8 kfa[4], kfb[4];
  auto loadK = [&](int kt2, b16x8* kf) {
    const short* kp = kb + (size_t)(kt2 * 32 + n16) * 64 + quad * 8;
    kf[0] = *(const b16x8*)kp;
    kf[1] = *(const b16x8*)(kp + 32);
    kf[2] = *(const b16x8*)(kp + 1024);
    kf[3] = *(const b16x8*)(kp + 1024 + 32);
  };
  auto step = [&](int kt2, b16x8* kf) {
    int kt0 = kt2 * 2;
    b16x8 vf[4];
    #pragma unroll
    for (int nt = 0; nt < 4; ++nt)
      vf[nt] = *(const b16x8*)(vb + (size_t)(nt * 16 + n16) * 768 + kt2 * 32 + quad * 8);
    bool doA = kt2 < nA;                // wave-uniform
    f32x4 sB0 = zero4, sB1 = zero4, sA0 = zero4, sA1 = zero4;
    sB0 = __builtin_amdgcn_mfma_f32_16x16x32_bf16(qB0, kf[0], sB0, 0, 0, 0);
    sB0 = __builtin_amdgcn_mfma_f32_16x16x32_bf16(qB1, kf[1], sB0, 0, 0, 0);
    sB1 = __builtin_amdgcn_mfma_f32_16x16x32_bf16(qB0, kf[2], sB1, 0, 0, 0);
    sB1 = __builtin_amdgcn_mfma_f32_16x16x32_bf16(qB1, kf[3], sB1, 0, 0, 0);
    if (doA) {
      sA0 = __builtin_amdgcn_mfma_f32_16x16x32_bf16(qA0, kf[0], sA0, 0, 0, 0);
      sA0 = __builtin_amdgcn_mfma_f32_16x16x32_bf16(qA1, kf[1], sA0, 0, 0, 0);
      sA1 = __builtin_amdgcn_mfma_f32_16x16x32_bf16(qA0, kf[2], sA1, 0, 0, 0);
      sA1 = __builtin_amdgcn_mfma_f32_16x16x32_bf16(qA1, kf[3], sA1, 0, 0, 0);
    }
    float btB0 = (kt0 <= qtB) ? btL[wv][kt0 - qtB + 47] : -1e30f;
    float btB1 = (kt0 + 1 <= qtB) ? btL[wv][kt0 + 1 - qtB + 47] : -1e30f;
    #pragma unroll
    for (int r = 0; r < 4; ++r) {
      float e0 = __expf(sB0[r] + btB0 + bp4[r]);
      float e1 = __expf(sB1[r] + btB1 + bp4[r]);
      psB[r] += e0 + e1;
      P[wv][1][quad * 4 + r][n16]      = brne(e0);
      P[wv][1][quad * 4 + r][16 + n16] = brne(e1);
    }
    if (doA) {
      float btA0 = (kt0 <= qtA) ? btL[wv][kt0 - qtA + 47] : -1e30f;
      float btA1 = (kt0 + 1 <= qtA) ? btL[wv][kt0 + 1 - qtA + 47] : -1e30f;
      #pragma unroll
      for (int r = 0; r < 4; ++r) {
        float e0 = __expf(sA0[r] + btA0 + bp4[r]);
        float e1 = __expf(sA1[r] + btA1 + bp4[r]);
        psA[r] += e0 + e1;
        P[wv][0][quad * 4 + r][n16]      = brne(e0);
        P[wv][0][quad * 4 + r][16 + n16] = brne(e1);
      }
    }
    b16x8 pfB = *(const b16x8*)&P[wv][1][n16][quad * 8];
    #pragma unroll
    for (int nt = 0; nt < 4; ++nt)
      oB[nt] = __builtin_amdgcn_mfma_f32_16x16x32_bf16(pfB, vf[nt], oB[nt], 0, 0, 0);
    if (doA) {
      b16x8 pfA = *(const b16x8*)&P[wv][0][n16][quad * 8];
      #pragma unroll
      for (int nt = 0; nt < 4; ++nt)
        oA[nt] = __builtin_amdgcn_mfma_f32_16x16x32_bf16(pfA, vf[nt], oA[nt], 0, 0, 0);
    }
  };

  // interleaved split-K: wave wv takes kt2 = wv, wv+2, ...
  loadK(wv, kfa);
  for (int kt2 = wv; kt2 < nB; kt2 += 4) {
    if (kt2 + 2 < nB) loadK(kt2 + 2, kfb);
    step(kt2, kfa);
    if (kt2 + 2 < nB) {
      if (kt2 + 4 < nB) loadK(kt2 + 4, kfa);
      step(kt2 + 2, kfb);
    }
  }

  // per-wave psum reduce over the 16 kn lanes
  #pragma unroll
  for (int r = 0; r < 4; ++r) {
    float sA = psA[r], sB = psB[r];
    sA += __shfl_xor(sA, 1); sA += __shfl_xor(sA, 2);
    sA += __shfl_xor(sA, 4); sA += __shfl_xor(sA, 8);
    sB += __shfl_xor(sB, 1); sB += __shfl_xor(sB, 2);
    sB += __shfl_xor(sB, 4); sB += __shfl_xor(sB, 8);
    psA[r] = sA; psB[r] = sB;
  }

  // cross-wave combine: wave0 writes its B partial to slot 1, wave1 writes A
  // partial to slot 0; barrier; wave0 finalizes A, wave1 finalizes B.
  {
    f32x4* oW = (wv == 0) ? oB : oA;
    float* psW = (wv == 0) ? psB : psA;
    int slot = 1 - wv;
    #pragma unroll
    for (int nt = 0; nt < 4; ++nt)
      #pragma unroll
      for (int r = 0; r < 4; ++r)
        Ox[slot][quad * 4 + r][nt * 16 + n16] = oW[nt][r];
    if (n16 == 0) {
      #pragma unroll
      for (int r = 0; r < 4; ++r) Ps[slot][quad * 4 + r] = psW[r];
    }
  }
  __syncthreads();
  {
    f32x4* oF = (wv == 0) ? oA : oB;
    float* psF = (wv == 0) ? psA : psB;
    int qt = (wv == 0) ? qtA : qtB;
    float inv[4];
    #pragma unroll
    for (int r = 0; r < 4; ++r)
      inv[r] = 1.0f / (psF[r] + Ps[wv][quad * 4 + r]);
    #pragma unroll
    for (int nt = 0; nt < 4; ++nt) {
      int c = h * 64 + nt * 16 + n16;
      #pragma unroll
      for (int r = 0; r < 4; ++r) {
        int qn = quad * 4 + r;
        float val = (oF[nt][r] + Ox[wv][qn][nt * 16 + n16]) * inv[r];
        yatt[((size_t)b * 768 + qn * 48 + qt) * 512 + c] = f2b(val);
      }
    }
  }
}

// ---------------------------------------------------------------------------
// proj: yatt(12288x512,bf16) @ WoT -> out fp32 (software-pipelined staging)
// ---------------------------------------------------------------------------
__global__ __launch_bounds__(256) void proj_kernel(
    const short* __restrict__ yatt, const short* __restrict__ WT,
    float* __restrict__ out)
{
  __shared__ short As[128][32];
  __shared__ short Bs[128][32];
  int tid = threadIdx.x;
  int w = tid >> 6, lane = tid & 63, n16 = lane & 15, quad = lane >> 4;
  int row0 = blockIdx.x * 128;
  int ncol0 = blockIdx.y * 128;
  const short* Wt = WT + (size_t)3 * 262144;

  f32x4 zero4 = {0.f, 0.f, 0.f, 0.f};
  f32x4 acc[4][4];
  #pragma unroll
  for (int mt = 0; mt < 4; ++mt)
    #pragma unroll
    for (int nt = 0; nt < 4; ++nt) acc[mt][nt] = zero4;

  int srow = tid >> 1, sch = (tid & 1) * 16;
  const short* ga = yatt + (size_t)(row0 + srow) * 512 + sch;
  const short* gb = Wt + (size_t)(ncol0 + srow) * 512 + sch;
  int wm = (w >> 1) * 64, wn = (w & 1) * 64;

  b16x8 a0 = *(const b16x8*)(ga);
  b16x8 a1 = *(const b16x8*)(ga + 8);
  b16x8 b0 = *(const b16x8*)(gb);
  b16x8 b1 = *(const b16x8*)(gb + 8);

  for (int kt = 0; kt < 16; ++kt) {
    __syncthreads();
    *(b16x8*)&As[srow][sch]     = a0;
    *(b16x8*)&As[srow][sch + 8] = a1;
    *(b16x8*)&Bs[srow][sch]     = b0;
    *(b16x8*)&Bs[srow][sch + 8] = b1;
    __syncthreads();
    if (kt < 15) {
      ga += 32; gb += 32;
      a0 = *(const b16x8*)(ga);
      a1 = *(const b16x8*)(ga + 8);
      b0 = *(const b16x8*)(gb);
      b1 = *(const b16x8*)(gb + 8);
    }
    b16x8 af[4], bf[4];
    #pragma unroll
    for (int mt = 0; mt < 4; ++mt) af[mt] = *(const b16x8*)&As[wm + mt * 16 + n16][quad * 8];
    #pragma unroll
    for (int nt = 0; nt < 4; ++nt) bf[nt] = *(const b16x8*)&Bs[wn + nt * 16 + n16][quad * 8];
    #pragma unroll
    for (int mt = 0; mt < 4; ++mt)
      #pragma unroll
      for (int nt = 0; nt < 4; ++nt)
        acc[mt][nt] = __builtin_amdgcn_mfma_f32_16x16x32_bf16(af[mt], bf[nt], acc[mt][nt], 0, 0, 0);
  }

  #pragma unroll
  for (int mt = 0; mt < 4; ++mt) {
    int rowb = row0 + wm + mt * 16 + quad * 4;
    #pragma unroll
    for (int nt = 0; nt < 4; ++nt) {
      int colg = ncol0 + wn + nt * 16 + n16;
      #pragma unroll
      for (int r = 0; r < 4; ++r)
        out[(size_t)(rowb + r) * 512 + colg] = acc[mt][nt][r];
    }
  }
}

// ---------------------------------------------------------------------------
extern "C" void kernel_launch(void* const* d_in, const int* in_sizes, int n_in,
                              void* d_out, int out_size, void* d_ws, size_t ws_size,
                              hipStream_t stream) {
  const float* x    = (const float*)d_in[0];
  const float* Wq   = (const float*)d_in[1];
  const float* Wk   = (const float*)d_in[2];
  const float* Wv   = (const float*)d_in[3];
  const float* Wo   = (const float*)d_in[4];
  const float* relT = (const float*)d_in[5];
  const float* relP = (const float*)d_in[6];

  char* wsb = (char*)d_ws;
  const size_t SZ = (size_t)BL_ * C_ * 2;
  short* xb  = (short*)(wsb);
  short* WT  = (short*)(wsb + SZ);
  short* qb  = (short*)(wsb + SZ + 2097152);
  short* kb  = (short*)(wsb + 2 * SZ + 2097152);
  short* vTb = (short*)(wsb + 3 * SZ + 2097152);
  short* yat = (short*)(wsb + 4 * SZ + 2097152 + 4096);

  prep_kernel<<<dim3(4096), dim3(256), 0, stream>>>(x, Wq, Wk, Wv, Wo, xb, WT);
  qkv_kernel<<<dim3(96, 12), dim3(256), 0, stream>>>(xb, WT, qb, kb, vTb);
  attn_kernel<<<dim3(3072), dim3(128), 0, stream>>>(qb, kb, vTb, relT, relP, yat);
  proj_kernel<<<dim3(96, 4), dim3(256), 0, stream>>>(yat, WT, (float*)d_out);
}

// Round 9
// 210.340 us; speedup vs baseline: 1.0048x; 1.0048x over previous
//
#include <hip/hip_runtime.h>
#include <hip/hip_bf16.h>
#include <math.h>

#define B_  16
#define N_  16
#define T_  48
#define C_  512
#define H_  8
#define HD_ 64
#define L_  768
#define BL_ 12288

typedef __attribute__((ext_vector_type(8))) short b16x8;
typedef __attribute__((ext_vector_type(4))) float f32x4;
typedef __attribute__((ext_vector_type(4))) unsigned int u32x4;

__device__ __forceinline__ short f2b(float f) {
  __hip_bfloat16 h = __float2bfloat16(f);
  return *reinterpret_cast<short*>(&h);
}
// pack two finite floats -> (bf16(hi)<<16)|bf16(lo), RNE
__device__ __forceinline__ unsigned pk2(float lo, float hi) {
  unsigned a = __float_as_uint(lo), b = __float_as_uint(hi);
  a += 0x7fffu + ((a >> 16) & 1u);
  b += 0x7fffu + ((b >> 16) & 1u);
  return (a >> 16) | (b & 0xffff0000u);
}

// ---------------------------------------------------------------------------
// prep (weights only): cast+transpose into WT[mat][n][k]; Wq pre-scaled 1/8.
// ---------------------------------------------------------------------------
__global__ __launch_bounds__(256) void prep_kernel(
    const float* __restrict__ Wq, const float* __restrict__ Wk,
    const float* __restrict__ Wv, const float* __restrict__ Wo,
    short* __restrict__ WT)
{
  __shared__ float tile[32][33];
  int idx = blockIdx.x;
  int tid = threadIdx.x;
  int mat = idx >> 8, rem = idx & 255;
  const float* W = (mat == 0) ? Wq : (mat == 1) ? Wk : (mat == 2) ? Wv : Wo;
  float scale = (mat == 0) ? 0.125f : 1.0f;
  int k0 = (rem >> 4) * 32, n0 = (rem & 15) * 32;
  int tx = tid & 31, ty = tid >> 5;
  for (int i = ty; i < 32; i += 8) tile[i][tx] = W[(size_t)(k0 + i) * 512 + n0 + tx];
  __syncthreads();
  short* dst = WT + (size_t)mat * 262144;
  for (int i = ty; i < 32; i += 8)
    dst[(size_t)(n0 + i) * 512 + k0 + tx] = f2b(tile[tx][i] * scale);
}

// ---------------------------------------------------------------------------
// QKV GEMM: A staged directly from fp32 x (converted in-register), time-major
// permuted M-rows (rr = pt*16+pn), LDS-staged epilogue.
//   q2,k2: [b][h][t][n][d]   vT3: [b][h][d][kt2][kn*2+ktl]
// ---------------------------------------------------------------------------
__global__ __launch_bounds__(256) void qkv_kernel(
    const float* __restrict__ x, const short* __restrict__ WT,
    short* __restrict__ q2, short* __restrict__ k2, short* __restrict__ vT3)
{
  __shared__ short smem[8192];              // As/Bs in K-loop; Ls in epilogue
  short (*As)[32] = (short(*)[32])smem;
  short (*Bs)[32] = (short(*)[32])(smem + 4096);
  int tid = threadIdx.x;
  int w = tid >> 6, lane = tid & 63, n16 = lane & 15, quad = lane >> 4;
  int bm = blockIdx.x, bn = blockIdx.y;
  int mat = bn >> 2;
  int ncol0 = (bn & 3) * 128;
  const short* Wt = WT + (size_t)mat * 262144;
  int bq = bm / 6;
  int rr0 = (bm % 6) * 128;

  f32x4 zero4 = {0.f, 0.f, 0.f, 0.f};
  f32x4 acc[4][4];
  #pragma unroll
  for (int mt = 0; mt < 4; ++mt)
    #pragma unroll
    for (int nt = 0; nt < 4; ++nt) acc[mt][nt] = zero4;

  int srow = tid >> 1, sch = (tid & 1) * 16;
  int rr = rr0 + srow;
  int pt = rr >> 4, pn = rr & 15;           // permuted row -> l = pn*48+pt
  const float* ga = x + ((size_t)bq * 768 + pn * 48 + pt) * 512 + sch;
  const short* gb = Wt + (size_t)(ncol0 + srow) * 512 + sch;
  int wm = (w >> 1) * 64, wn = (w & 1) * 64;

  float4 fa0 = *(const float4*)(ga);
  float4 fa1 = *(const float4*)(ga + 4);
  float4 fa2 = *(const float4*)(ga + 8);
  float4 fa3 = *(const float4*)(ga + 12);
  b16x8 b0 = *(const b16x8*)(gb);
  b16x8 b1 = *(const b16x8*)(gb + 8);

  for (int kt = 0; kt < 16; ++kt) {
    u32x4 lo = {pk2(fa0.x, fa0.y), pk2(fa0.z, fa0.w), pk2(fa1.x, fa1.y), pk2(fa1.z, fa1.w)};
    u32x4 hi = {pk2(fa2.x, fa2.y), pk2(fa2.z, fa2.w), pk2(fa3.x, fa3.y), pk2(fa3.z, fa3.w)};
    __syncthreads();
    *(b16x8*)&As[srow][sch]     = *reinterpret_cast<b16x8*>(&lo);
    *(b16x8*)&As[srow][sch + 8] = *reinterpret_cast<b16x8*>(&hi);
    *(b16x8*)&Bs[srow][sch]     = b0;
    *(b16x8*)&Bs[srow][sch + 8] = b1;
    __syncthreads();
    if (kt < 15) {                          // prefetch hides under MFMAs
      ga += 32; gb += 32;
      fa0 = *(const float4*)(ga);
      fa1 = *(const float4*)(ga + 4);
      fa2 = *(const float4*)(ga + 8);
      fa3 = *(const float4*)(ga + 12);
      b0 = *(const b16x8*)(gb);
      b1 = *(const b16x8*)(gb + 8);
    }
    b16x8 af[4], bf[4];
    #pragma unroll
    for (int mt = 0; mt < 4; ++mt) af[mt] = *(const b16x8*)&As[wm + mt * 16 + n16][quad * 8];
    #pragma unroll
    for (int nt = 0; nt < 4; ++nt) bf[nt] = *(const b16x8*)&Bs[wn + nt * 16 + n16][quad * 8];
    #pragma unroll
    for (int mt = 0; mt < 4; ++mt)
      #pragma unroll
      for (int nt = 0; nt < 4; ++nt)
        acc[mt][nt] = __builtin_amdgcn_mfma_f32_16x16x32_bf16(af[mt], bf[nt], acc[mt][nt], 0, 0, 0);
  }

  // epilogue: 4 chunks of 32 tile-rows staged through LDS, vector stores out
  short (*Ls)[136] = (short(*)[136])smem;
  for (int c = 0; c < 4; ++c) {
    __syncthreads();
    if ((w >> 1) == (c >> 1)) {
      int mtb = (c & 1) * 2;
      #pragma unroll
      for (int mi = 0; mi < 2; ++mi) {
        #pragma unroll
        for (int nt = 0; nt < 4; ++nt)
          #pragma unroll
          for (int r = 0; r < 4; ++r)
            Ls[mi * 16 + quad * 4 + r][wn + nt * 16 + n16] = f2b(acc[mtb + mi][nt][r]);
      }
    }
    __syncthreads();
    int rrc = rr0 + c * 32;
    if (mat != 2) {
      short* dst = (mat == 0) ? q2 : k2;
      int row = tid >> 3, c0 = (tid & 7) * 16;
      int hhg = (ncol0 + c0) >> 6, d0 = (ncol0 + c0) & 63;
      short* dp = dst + ((size_t)(bq * 8 + hhg) * 768 + rrc + row) * 64 + d0;
      *(b16x8*)dp       = *(b16x8*)&Ls[row][c0];
      *(b16x8*)(dp + 8) = *(b16x8*)&Ls[row][c0 + 8];
    } else {
      // vT3: offset = d*768 + kt2c*32 + (kn*2+ktl); chunk rows idx = ktl*16+kn
      int cp = tid & 127;                   // local col
      int half = tid >> 7;                  // k32 halves
      int colg = ncol0 + cp;
      int hhg = colg >> 6, d0 = colg & 63;
      short t[16];
      #pragma unroll
      for (int j = 0; j < 16; ++j)
        t[j] = Ls[(j & 1) * 16 + half * 8 + (j >> 1)][cp];
      int kt2c = rrc >> 5;
      short* dp = vT3 + ((size_t)(bq * 8 + hhg) * 64 + d0) * 768 + kt2c * 32 + half * 16;
      *(b16x8*)dp       = *(b16x8*)t;
      *(b16x8*)(dp + 8) = *(b16x8*)(t + 8);
    }
  }
}

// ---------------------------------------------------------------------------
// Attention: time-major tiles, wave = (b,h,{qt,47-qt}), 25 balanced steps.
// S^T = K·Q^T; P stays ENTIRELY in registers: with PV K-ordering kn*2+ktl the
// exp'd C-frag IS the K=32 A-frag. No P LDS round-trip, biases multiplicative.
// ---------------------------------------------------------------------------
__global__ __launch_bounds__(128) void attn_kernel(
    const short* __restrict__ q2, const short* __restrict__ k2,
    const short* __restrict__ vT3,
    const float* __restrict__ relT, const float* __restrict__ relP,
    short* __restrict__ yatt)
{
  __shared__ float btL[96];                 // exp(relT) for this head

  int tid = threadIdx.x;
  int wv = tid >> 6, lane = tid & 63, n16 = lane & 15, quad = lane >> 4;
  int blk = blockIdx.x;
  int h = blk & 7;                          // XCD-locality
  int g = blk >> 3;
  int pg = g % 12, b = g / 12;
  int pair = pg * 2 + wv;
  int qtA = pair, qtB = 47 - pair;
  int nA = (qtA + 2) >> 1, nB = (qtB + 2) >> 1;   // nA + nB == 25

  // both waves write identical values -> benign race, no barrier needed
  btL[lane] = __expf(relT[(lane < 95 ? lane : 94) * 8 + h]);
  if (lane < 32) btL[64 + lane] = __expf(relT[((64 + lane) < 95 ? 64 + lane : 94) * 8 + h]);

  // exp(bias_p): lane regs kn = quad*4+r, lane col qn = n16
  float ebp4[4];
  #pragma unroll
  for (int r = 0; r < 4; ++r)
    ebp4[r] = __expf(relP[((quad * 4 + r) - n16 + 15) * 8 + h]);

  size_t bh = (size_t)(b * 8 + h);
  const short* qb = q2 + bh * 49152;
  const short* kb = k2 + bh * 49152;
  const short* vb = vT3 + bh * 49152;

  b16x8 qA0 = *(const b16x8*)(qb + (qtA * 16 + n16) * 64 + quad * 8);
  b16x8 qA1 = *(const b16x8*)(qb + (qtA * 16 + n16) * 64 + quad * 8 + 32);
  b16x8 qB0 = *(const b16x8*)(qb + (qtB * 16 + n16) * 64 + quad * 8);
  b16x8 qB1 = *(const b16x8*)(qb + (qtB * 16 + n16) * 64 + quad * 8 + 32);

  f32x4 zero4 = {0.f, 0.f, 0.f, 0.f};
  f32x4 oA[4], oB[4];
  float psA = 0.f, psB = 0.f;
  #pragma unroll
  for (int nt = 0; nt < 4; ++nt) { oA[nt] = zero4; oB[nt] = zero4; }

  b16x8 kfa[4], kfb[4], vfa[4], vfb[4];
  auto loadKV = [&](int kt2, b16x8* kf, b16x8* vf) {
    const short* kp = kb + (size_t)(kt2 * 32 + n16) * 64 + quad * 8;
    kf[0] = *(const b16x8*)kp;
    kf[1] = *(const b16x8*)(kp + 32);
    kf[2] = *(const b16x8*)(kp + 1024);
    kf[3] = *(const b16x8*)(kp + 1024 + 32);
    #pragma unroll
    for (int nt = 0; nt < 4; ++nt)
      vf[nt] = *(const b16x8*)(vb + (size_t)(nt * 16 + n16) * 768 + kt2 * 32 + quad * 8);
  };
  auto step = [&](int kt2, const b16x8* kf, const b16x8* vf) {
    int kt0 = kt2 * 2;
    bool doA = kt2 < nA;                    // wave-uniform
    f32x4 sB0 = zero4, sB1 = zero4, sA0 = zero4, sA1 = zero4;
    sB0 = __builtin_amdgcn_mfma_f32_16x16x32_bf16(kf[0], qB0, sB0, 0, 0, 0);
    sB0 = __builtin_amdgcn_mfma_f32_16x16x32_bf16(kf[1], qB1, sB0, 0, 0, 0);
    sB1 = __builtin_amdgcn_mfma_f32_16x16x32_bf16(kf[2], qB0, sB1, 0, 0, 0);
    sB1 = __builtin_amdgcn_mfma_f32_16x16x32_bf16(kf[3], qB1, sB1, 0, 0, 0);
    if (doA) {
      sA0 = __builtin_amdgcn_mfma_f32_16x16x32_bf16(kf[0], qA0, sA0, 0, 0, 0);
      sA0 = __builtin_amdgcn_mfma_f32_16x16x32_bf16(kf[1], qA1, sA0, 0, 0, 0);
      sA1 = __builtin_amdgcn_mfma_f32_16x16x32_bf16(kf[2], qA0, sA1, 0, 0, 0);
      sA1 = __builtin_amdgcn_mfma_f32_16x16x32_bf16(kf[3], qA1, sA1, 0, 0, 0);
    }
    {
      float eb0 = (kt0 <= qtB) ? btL[kt0 - qtB + 47] : 0.f;
      float eb1 = (kt0 + 1 <= qtB) ? btL[kt0 + 1 - qtB + 47] : 0.f;
      unsigned pw[4];
      #pragma unroll
      for (int r = 0; r < 4; ++r) {
        float e0 = __expf(sB0[r]) * (eb0 * ebp4[r]);
        float e1 = __expf(sB1[r]) * (eb1 * ebp4[r]);
        psB += e0 + e1;
        pw[r] = pk2(e0, e1);
      }
      u32x4 up = {pw[0], pw[1], pw[2], pw[3]};
      b16x8 pf = *reinterpret_cast<b16x8*>(&up);
      #pragma unroll
      for (int nt = 0; nt < 4; ++nt)
        oB[nt] = __builtin_amdgcn_mfma_f32_16x16x32_bf16(pf, vf[nt], oB[nt], 0, 0, 0);
    }
    if (doA) {
      float eb0 = (kt0 <= qtA) ? btL[kt0 - qtA + 47] : 0.f;
      float eb1 = (kt0 + 1 <= qtA) ? btL[kt0 + 1 - qtA + 47] : 0.f;
      unsigned pw[4];
      #pragma unroll
      for (int r = 0; r < 4; ++r) {
        float e0 = __expf(sA0[r]) * (eb0 * ebp4[r]);
        float e1 = __expf(sA1[r]) * (eb1 * ebp4[r]);
        psA += e0 + e1;
        pw[r] = pk2(e0, e1);
      }
      u32x4 up = {pw[0], pw[1], pw[2], pw[3]};
      b16x8 pf = *reinterpret_cast<b16x8*>(&up);
      #pragma unroll
      for (int nt = 0; nt < 4; ++nt)
        oA[nt] = __builtin_amdgcn_mfma_f32_16x16x32_bf16(pf, vf[nt], oA[nt], 0, 0, 0);
    }
  };

  loadKV(0, kfa, vfa);
  for (int kt2 = 0; kt2 < nB; kt2 += 2) {
    if (kt2 + 1 < nB) loadKV(kt2 + 1, kfb, vfb);
    step(kt2, kfa, vfa);
    if (kt2 + 1 < nB) {
      if (kt2 + 2 < nB) loadKV(kt2 + 2, kfa, vfa);
      step(kt2 + 1, kfb, vfb);
    }
  }

  // psum: in-lane sum over r already; reduce across quads (kn groups)
  psA += __shfl_xor(psA, 16); psA += __shfl_xor(psA, 32);
  psB += __shfl_xor(psB, 16); psB += __shfl_xor(psB, 32);

  // O C-layout: col=lane&15=d_local, row=quad*4+r=qn; pull qn's sum by shfl
  float invA[4], invB[4];
  #pragma unroll
  for (int r = 0; r < 4; ++r) {
    int qn = quad * 4 + r;
    invA[r] = 1.0f / __shfl(psA, qn);
    invB[r] = 1.0f / __shfl(psB, qn);
  }
  #pragma unroll
  for (int nt = 0; nt < 4; ++nt) {
    int c = h * 64 + nt * 16 + n16;
    #pragma unroll
    for (int r = 0; r < 4; ++r) {
      int qn = quad * 4 + r;
      yatt[((size_t)b * 768 + qn * 48 + qtA) * 512 + c] = f2b(oA[nt][r] * invA[r]);
      yatt[((size_t)b * 768 + qn * 48 + qtB) * 512 + c] = f2b(oB[nt][r] * invB[r]);
    }
  }
}

// ---------------------------------------------------------------------------
// proj: yatt(12288x512,bf16) @ WoT -> out fp32 (software-pipelined staging)
// ---------------------------------------------------------------------------
__global__ __launch_bounds__(256) void proj_kernel(
    const short* __restrict__ yatt, const short* __restrict__ WT,
    float* __restrict__ out)
{
  __shared__ short As[128][32];
  __shared__ short Bs[128][32];
  int tid = threadIdx.x;
  int w = tid >> 6, lane = tid & 63, n16 = lane & 15, quad = lane >> 4;
  int row0 = blockIdx.x * 128;
  int ncol0 = blockIdx.y * 128;
  const short* Wt = WT + (size_t)3 * 262144;

  f32x4 zero4 = {0.f, 0.f, 0.f, 0.f};
  f32x4 acc[4][4];
  #pragma unroll
  for (int mt = 0; mt < 4; ++mt)
    #pragma unroll
    for (int nt = 0; nt < 4; ++nt) acc[mt][nt] = zero4;

  int srow = tid >> 1, sch = (tid & 1) * 16;
  const short* ga = yatt + (size_t)(row0 + srow) * 512 + sch;
  const short* gb = Wt + (size_t)(ncol0 + srow) * 512 + sch;
  int wm = (w >> 1) * 64, wn = (w & 1) * 64;

  b16x8 a0 = *(const b16x8*)(ga);
  b16x8 a1 = *(const b16x8*)(ga + 8);
  b16x8 b0 = *(const b16x8*)(gb);
  b16x8 b1 = *(const b16x8*)(gb + 8);

  for (int kt = 0; kt < 16; ++kt) {
    __syncthreads();
    *(b16x8*)&As[srow][sch]     = a0;
    *(b16x8*)&As[srow][sch + 8] = a1;
    *(b16x8*)&Bs[srow][sch]     = b0;
    *(b16x8*)&Bs[srow][sch + 8] = b1;
    __syncthreads();
    if (kt < 15) {
      ga += 32; gb += 32;
      a0 = *(const b16x8*)(ga);
      a1 = *(const b16x8*)(ga + 8);
      b0 = *(const b16x8*)(gb);
      b1 = *(const b16x8*)(gb + 8);
    }
    b16x8 af[4], bf[4];
    #pragma unroll
    for (int mt = 0; mt < 4; ++mt) af[mt] = *(const b16x8*)&As[wm + mt * 16 + n16][quad * 8];
    #pragma unroll
    for (int nt = 0; nt < 4; ++nt) bf[nt] = *(const b16x8*)&Bs[wn + nt * 16 + n16][quad * 8];
    #pragma unroll
    for (int mt = 0; mt < 4; ++mt)
      #pragma unroll
      for (int nt = 0; nt < 4; ++nt)
        acc[mt][nt] = __builtin_amdgcn_mfma_f32_16x16x32_bf16(af[mt], bf[nt], acc[mt][nt], 0, 0, 0);
  }

  #pragma unroll
  for (int mt = 0; mt < 4; ++mt) {
    int rowb = row0 + wm + mt * 16 + quad * 4;
    #pragma unroll
    for (int nt = 0; nt < 4; ++nt) {
      int colg = ncol0 + wn + nt * 16 + n16;
      #pragma unroll
      for (int r = 0; r < 4; ++r)
        out[(size_t)(rowb + r) * 512 + colg] = acc[mt][nt][r];
    }
  }
}

// ---------------------------------------------------------------------------
extern "C" void kernel_launch(void* const* d_in, const int* in_sizes, int n_in,
                              void* d_out, int out_size, void* d_ws, size_t ws_size,
                              hipStream_t stream) {
  const float* x    = (const float*)d_in[0];
  const float* Wq   = (const float*)d_in[1];
  const float* Wk   = (const float*)d_in[2];
  const float* Wv   = (const float*)d_in[3];
  const float* Wo   = (const float*)d_in[4];
  const float* relT = (const float*)d_in[5];
  const float* relP = (const float*)d_in[6];

  char* wsb = (char*)d_ws;
  const size_t SZ = (size_t)BL_ * C_ * 2;
  short* WT  = (short*)(wsb);
  short* qb  = (short*)(wsb + 2097152);
  short* kb  = (short*)(wsb + 2097152 + SZ);
  short* vTb = (short*)(wsb + 2097152 + 2 * SZ);
  short* yat = (short*)(wsb + 2097152 + 3 * SZ + 4096);

  prep_kernel<<<dim3(1024), dim3(256), 0, stream>>>(Wq, Wk, Wv, Wo, WT);
  qkv_kernel<<<dim3(96, 12), dim3(256), 0, stream>>>(x, WT, qb, kb, vTb);
  attn_kernel<<<dim3(1536), dim3(128), 0, stream>>>(qb, kb, vTb, relT, relP, yat);
  proj_kernel<<<dim3(96, 4), dim3(256), 0, stream>>>(yat, WT, (float*)d_out);
}